// Round 9
// baseline (198.148 us; speedup 1.0000x reference)
//
#include <hip/hip_runtime.h>
#include <hip/hip_cooperative_groups.h>
#include <math.h>

namespace cg = cooperative_groups;

#define Bb 8
#define Tt 2048
#define Cc 1024
#define Hh 64
#define BT (Bb * Tt)          // 16384 tokens
#define SLOG2E 0.18033688011112042f   // 0.125 * log2(e)

typedef __attribute__((ext_vector_type(8))) short short8;
typedef __attribute__((ext_vector_type(4))) float floatx4;

__device__ inline unsigned short f2bf(float f) {
  unsigned int u = __builtin_bit_cast(unsigned int, f);
  u += 0x7fff + ((u >> 16) & 1);   // RNE
  return (unsigned short)(u >> 16);
}
__device__ inline float bf2f(unsigned short u) {
  unsigned int x = ((unsigned int)u) << 16;
  return __builtin_bit_cast(float, x);
}

// Fragment-major layouts (bf16):
//  WTf: [g=n16(12)][kc(32)][lane(64)][8]  (B-frag = base + lane*16B)
//  Qf/Kf: per 16-token tile [tile16][kc(2)][lane][8]
//  Vf: per 32-token tile [tile32][hs(4)][lane][8]

// ================= FUSED cooperative kernel =================
// grid 256 x 512. Phase 0: wconv (blocks 0..47). Phase 1: qkv (1 block =
// 64-token m-tile). Phase 2: attn (1 block = (b,j) q-tile pair). grid.sync
// between phases.
__global__ __launch_bounds__(512) void fused(
    const float* __restrict__ x,
    const float* __restrict__ Wq, const float* __restrict__ Wk,
    const float* __restrict__ Wv,
    unsigned short* __restrict__ WTf,
    unsigned short* __restrict__ Qf, unsigned short* __restrict__ Kf,
    unsigned short* __restrict__ Vf, float* __restrict__ out) {
  __shared__ __align__(16) unsigned char smemF[34304];
  cg::grid_group grid = cg::this_grid();

  int bid = blockIdx.x;
  int t = threadIdx.x;
  int wv = t >> 6, lane = t & 63;
  int lrow = lane & 15, quad = lane >> 4;

  // ---------- phase 0: W -> WTf ----------
  if (bid < 48) {
    int unit = bid * 2 + (t >> 8);     // 0..95
    int tt = t & 255;
    int w = unit >> 5;
    int kc = unit & 31;
    const float* __restrict__ W = (w == 0) ? Wq : (w == 1 ? Wk : Wv);
    int hg = tt >> 6, q_ = (tt >> 4) & 3, lr_ = tt & 15;
    int g = w * 4 + hg;
    int h = hg * 16 + lr_;
    unsigned short tmp[8];
#pragma unroll
    for (int j = 0; j < 8; ++j)
      tmp[j] = f2bf(W[(size_t)(kc * 32 + q_ * 8 + j) * Hh + h]);
    unsigned short* dst = &WTf[((size_t)(g * 32 + kc) * 64 + q_ * 16 + lr_) * 8];
    *(ushort4*)dst = make_ushort4(tmp[0], tmp[1], tmp[2], tmp[3]);
    *(ushort4*)(dst + 4) = make_ushort4(tmp[4], tmp[5], tmp[6], tmp[7]);
  }
  grid.sync();

  // ---------- phase 1: QKV projection (64-token tile per block) ----------
  {
    unsigned short* Af = (unsigned short*)smemF;   // dbuf 2 x 4096 ushorts
    int mt = bid;
    int wm = wv & 1;          // m-half: msubs wm*2, wm*2+1
    int wq = wv >> 1;         // n-quarter: groups wq*3..+2

    floatx4 acc[2][3];
#pragma unroll
    for (int i = 0; i < 2; ++i)
#pragma unroll
      for (int j = 0; j < 3; ++j)
#pragma unroll
        for (int r = 0; r < 4; ++r) acc[i][j][r] = 0.f;

    int srow = t >> 3, scg = t & 7;
    int skc2 = scg >> 2, squad = scg & 3;
    int sslot = ((srow >> 4) * 2 + skc2) * 512 +
                (squad * 16 + (((srow & 15) + squad + 4 * skc2) & 15)) * 8;
    const float* xp = x + (size_t)(mt * 64 + srow) * Cc + scg * 8;

    int aslot[2][2];
#pragma unroll
    for (int i = 0; i < 2; ++i)
#pragma unroll
      for (int kc2 = 0; kc2 < 2; ++kc2) {
        int ms = wm * 2 + i;
        aslot[i][kc2] = ((ms * 2 + kc2) * 512 +
                         (quad * 16 + ((lrow + quad + 4 * kc2) & 15)) * 8);
      }

    const unsigned short* wbase[3];
#pragma unroll
    for (int j = 0; j < 3; ++j)
      wbase[j] = WTf + (size_t)(wq * 3 + j) * 32 * 512 + lane * 8;

    // prologue: stage k-step 0 into buf 0
    {
      float4 v0 = *(const float4*)xp;
      float4 v1 = *(const float4*)(xp + 4);
      short8 a;
      a[0] = (short)f2bf(v0.x); a[1] = (short)f2bf(v0.y);
      a[2] = (short)f2bf(v0.z); a[3] = (short)f2bf(v0.w);
      a[4] = (short)f2bf(v1.x); a[5] = (short)f2bf(v1.y);
      a[6] = (short)f2bf(v1.z); a[7] = (short)f2bf(v1.w);
      *(short8*)&Af[sslot] = a;
    }
    __syncthreads();

    for (int kk = 0; kk < 16; ++kk) {
      int cur = kk & 1;
      float4 v0, v1;
      if (kk < 15) {
        v0 = *(const float4*)(xp + (kk + 1) * 64);
        v1 = *(const float4*)(xp + (kk + 1) * 64 + 4);
      }
      short8 bfr[3][2];
      int kg = kk * 2;
#pragma unroll
      for (int j = 0; j < 3; ++j)
#pragma unroll
        for (int kc2 = 0; kc2 < 2; ++kc2)
          bfr[j][kc2] = *(const short8*)(wbase[j] + (size_t)(kg + kc2) * 512);
      short8 af[2][2];
#pragma unroll
      for (int i = 0; i < 2; ++i)
#pragma unroll
        for (int kc2 = 0; kc2 < 2; ++kc2)
          af[i][kc2] = *(const short8*)&Af[cur * 4096 + aslot[i][kc2]];
#pragma unroll
      for (int i = 0; i < 2; ++i)
#pragma unroll
        for (int j = 0; j < 3; ++j) {
          acc[i][j] = __builtin_amdgcn_mfma_f32_16x16x32_bf16(af[i][0], bfr[j][0], acc[i][j], 0, 0, 0);
          acc[i][j] = __builtin_amdgcn_mfma_f32_16x16x32_bf16(af[i][1], bfr[j][1], acc[i][j], 0, 0, 0);
        }
      if (kk < 15) {
        short8 a;
        a[0] = (short)f2bf(v0.x); a[1] = (short)f2bf(v0.y);
        a[2] = (short)f2bf(v0.z); a[3] = (short)f2bf(v0.w);
        a[4] = (short)f2bf(v1.x); a[5] = (short)f2bf(v1.y);
        a[6] = (short)f2bf(v1.z); a[7] = (short)f2bf(v1.w);
        *(short8*)&Af[(1 - cur) * 4096 + sslot] = a;
        __syncthreads();
      }
    }

    // epilogue: D -> LDS (64 x 208) -> frag-major global
    __syncthreads();
    unsigned short* Dt = (unsigned short*)smemF;
#pragma unroll
    for (int i = 0; i < 2; ++i)
#pragma unroll
      for (int j = 0; j < 3; ++j) {
        int col = (wq * 3 + j) * 16 + lrow;
        int rowb = (wm * 2 + i) * 16 + quad * 4;
#pragma unroll
        for (int r = 0; r < 4; ++r)
          Dt[(rowb + r) * 208 + col] = f2bf(acc[i][j][r]);
      }
    __syncthreads();
#pragma unroll
    for (int fi = 0; fi < 3; ++fi) {
      int idx = fi * 512 + t;            // 0..1535
      int tile = idx >> 6, lane_s = idx & 63;
      if (tile < 16) {
        // Q (tile<8) / K frag tiles
        int which = tile >> 3;
        int sub = tile & 7;
        int g2 = sub >> 1, kc = sub & 1;
        int tokrow = g2 * 16 + (lane_s & 15);
        int hbase = which * 64 + kc * 32 + (lane_s >> 4) * 8;
        short8 v = *(const short8*)&Dt[tokrow * 208 + hbase];
        unsigned short* dstf = which ? Kf : Qf;
        *(short8*)&dstf[((size_t)(mt * 4 + g2) * 2 + kc) * 512 + lane_s * 8] = v;
      } else {
        int sub = tile - 16;
        int t32 = sub >> 2, hs = sub & 3;
        int hcol = 128 + hs * 16 + (lane_s & 15);
        int tok0 = t32 * 32 + (lane_s >> 4) * 8;
        unsigned short tmp[8];
#pragma unroll
        for (int jj = 0; jj < 8; ++jj) tmp[jj] = Dt[(tok0 + jj) * 208 + hcol];
        unsigned short* dv = &Vf[((size_t)(mt * 2 + t32) * 4 + hs) * 512 + lane_s * 8];
        *(ushort4*)dv = make_ushort4(tmp[0], tmp[1], tmp[2], tmp[3]);
        *(ushort4*)(dv + 4) = make_ushort4(tmp[4], tmp[5], tmp[6], tmp[7]);
      }
    }
  }
  grid.sync();

  // ---------- phase 2: causal attention ----------
  {
    unsigned short* Pall = (unsigned short*)smemF;
    unsigned short* Ocomb = (unsigned short*)smemF;
    float* Lcomb = (float*)(smemF + 32768);
    unsigned short* Pw = Pall + wv * 2048;

    int b = bid >> 5;
    int j = bid & 31;

    short8 ones;
#pragma unroll
    for (int i = 0; i < 8; ++i) ones[i] = (short)0x3F80;

    for (int half = 0; half < 2; ++half) {
      int qt = half ? (63 - j) : j;
      int q0 = qt * 32;
      int nkt = (qt >> 1) + 1;
      int qtile16 = b * 128 + qt * 2;

      short8 aq[2][2];
#pragma unroll
      for (int qs = 0; qs < 2; ++qs)
#pragma unroll
        for (int kc = 0; kc < 2; ++kc)
          aq[qs][kc] = *(const short8*)
              &Qf[((size_t)(qtile16 + qs) * 2 + kc) * 512 + lane * 8];

      floatx4 acc_o[2][4];
      floatx4 acc_l[2];
#pragma unroll
      for (int qs = 0; qs < 2; ++qs) {
#pragma unroll
        for (int r = 0; r < 4; ++r) acc_l[qs][r] = 0.f;
#pragma unroll
        for (int hs = 0; hs < 4; ++hs)
#pragma unroll
          for (int r = 0; r < 4; ++r) acc_o[qs][hs][r] = 0.f;
      }

      for (int kt = wv; kt < nkt; kt += 8) {
        int ktile16 = b * 128 + kt * 4;
        int ktile32 = b * 64 + kt * 2;
        short8 kf[4][2], vf[4][2];
#pragma unroll
        for (int sn = 0; sn < 4; ++sn)
#pragma unroll
          for (int kc = 0; kc < 2; ++kc)
            kf[sn][kc] = *(const short8*)
                &Kf[((size_t)(ktile16 + sn) * 2 + kc) * 512 + lane * 8];
#pragma unroll
        for (int hs = 0; hs < 4; ++hs)
#pragma unroll
          for (int kc = 0; kc < 2; ++kc)
            vf[hs][kc] = *(const short8*)
                &Vf[((size_t)(ktile32 + kc) * 4 + hs) * 512 + lane * 8];

        floatx4 s[2][4];
#pragma unroll
        for (int qs = 0; qs < 2; ++qs)
#pragma unroll
          for (int sn = 0; sn < 4; ++sn) {
            floatx4 z;
#pragma unroll
            for (int r = 0; r < 4; ++r) z[r] = 0.f;
            z = __builtin_amdgcn_mfma_f32_16x16x32_bf16(aq[qs][0], kf[sn][0], z, 0, 0, 0);
            z = __builtin_amdgcn_mfma_f32_16x16x32_bf16(aq[qs][1], kf[sn][1], z, 0, 0, 0);
            s[qs][sn] = z;
          }

        bool diag = (kt == nkt - 1);
#pragma unroll
        for (int qs = 0; qs < 2; ++qs)
#pragma unroll
          for (int sn = 0; sn < 4; ++sn) {
            int k5 = (sn & 1) * 16 + lrow;
            int slot = qs * 2 + (sn >> 1);
            int rlbase = (k5 >> 3) * 16;
#pragma unroll
            for (int r = 0; r < 4; ++r) {
              float v = s[qs][sn][r] * SLOG2E;
              if (diag) {
                int gk = kt * 64 + sn * 16 + lrow;
                int gq = q0 + qs * 16 + quad * 4 + r;
                if (gk > gq) v = -INFINITY;
              }
              float p = exp2f(v);
              Pw[slot * 512 + (rlbase + quad * 4 + r) * 8 + (k5 & 7)] = f2bf(p);
            }
          }

        short8 ap[2][2];
#pragma unroll
        for (int qs = 0; qs < 2; ++qs)
#pragma unroll
          for (int kc = 0; kc < 2; ++kc)
            ap[qs][kc] = *(const short8*)&Pw[(qs * 2 + kc) * 512 + lane * 8];

#pragma unroll
        for (int qs = 0; qs < 2; ++qs) {
          acc_l[qs] = __builtin_amdgcn_mfma_f32_16x16x32_bf16(ap[qs][0], ones, acc_l[qs], 0, 0, 0);
          acc_l[qs] = __builtin_amdgcn_mfma_f32_16x16x32_bf16(ap[qs][1], ones, acc_l[qs], 0, 0, 0);
#pragma unroll
          for (int hs = 0; hs < 4; ++hs) {
            acc_o[qs][hs] = __builtin_amdgcn_mfma_f32_16x16x32_bf16(ap[qs][0], vf[hs][0], acc_o[qs][hs], 0, 0, 0);
            acc_o[qs][hs] = __builtin_amdgcn_mfma_f32_16x16x32_bf16(ap[qs][1], vf[hs][1], acc_o[qs][hs], 0, 0, 0);
          }
        }
      }

      // combine 8 wave-partials
#pragma unroll
      for (int qs = 0; qs < 2; ++qs)
#pragma unroll
        for (int hs = 0; hs < 4; ++hs) {
          int s8 = qs * 4 + hs;
          *(ushort4*)&Ocomb[((wv * 8 + s8) * 64 + lane) * 4] =
              make_ushort4(f2bf(acc_o[qs][hs][0]), f2bf(acc_o[qs][hs][1]),
                           f2bf(acc_o[qs][hs][2]), f2bf(acc_o[qs][hs][3]));
        }
      if (lrow == 0) {
#pragma unroll
        for (int qs = 0; qs < 2; ++qs)
#pragma unroll
          for (int r = 0; r < 4; ++r)
            Lcomb[wv * 32 + qs * 16 + quad * 4 + r] = acc_l[qs][r];
      }
      __syncthreads();

      {
        int qsub = wv >> 2, hs = wv & 3;
        float o[4] = {0.f, 0.f, 0.f, 0.f};
#pragma unroll
        for (int w = 0; w < 8; ++w) {
          ushort4 pk = *(const ushort4*)&Ocomb[((w * 8 + wv) * 64 + lane) * 4];
          o[0] += bf2f(pk.x); o[1] += bf2f(pk.y);
          o[2] += bf2f(pk.z); o[3] += bf2f(pk.w);
        }
#pragma unroll
        for (int r = 0; r < 4; ++r) {
          float lv = 0.f;
#pragma unroll
          for (int w = 0; w < 8; ++w)
            lv += Lcomb[w * 32 + qsub * 16 + quad * 4 + r];
          int row = q0 + qsub * 16 + quad * 4 + r;
          out[(size_t)(b * Tt + row) * Hh + hs * 16 + lrow] = o[r] / lv;
        }
      }
      __syncthreads();
    }
  }
}

// ================= Fallback (non-cooperative) kernels =================
__global__ __launch_bounds__(256) void wconv2(
    const float* __restrict__ Wq, const float* __restrict__ Wk,
    const float* __restrict__ Wv, unsigned short* __restrict__ WTf) {
  int bid = blockIdx.x;
  int w = bid >> 5;
  int kc = bid & 31;
  const float* __restrict__ W = (w == 0) ? Wq : (w == 1 ? Wk : Wv);
  int t = threadIdx.x;
  int hg = t >> 6, quad = (t >> 4) & 3, lrow = t & 15;
  int g = w * 4 + hg;
  int h = hg * 16 + lrow;
  unsigned short tmp[8];
#pragma unroll
  for (int j = 0; j < 8; ++j)
    tmp[j] = f2bf(W[(size_t)(kc * 32 + quad * 8 + j) * Hh + h]);
  unsigned short* dst = &WTf[((size_t)(g * 32 + kc) * 64 + quad * 16 + lrow) * 8];
  *(ushort4*)dst = make_ushort4(tmp[0], tmp[1], tmp[2], tmp[3]);
  *(ushort4*)(dst + 4) = make_ushort4(tmp[4], tmp[5], tmp[6], tmp[7]);
}

__global__ __launch_bounds__(256) void qkv7(
    const float* __restrict__ x, const unsigned short* __restrict__ WTf,
    unsigned short* __restrict__ Qf, unsigned short* __restrict__ Kf,
    unsigned short* __restrict__ Vf) {
  __shared__ __align__(16) unsigned short smem7[6656];
  int mt = blockIdx.x;
  int t = threadIdx.x;
  int wv = t >> 6, lane = t & 63;
  int lrow = lane & 15, quad = lane >> 4;
  floatx4 acc[2][3];
#pragma unroll
  for (int g2 = 0; g2 < 2; ++g2)
#pragma unroll
    for (int j = 0; j < 3; ++j)
#pragma unroll
      for (int r = 0; r < 4; ++r) acc[g2][j][r] = 0.f;
  int srow = t >> 3, scg = t & 7;
  int skc2 = scg >> 2, squad = scg & 3;
  int sslot = ((srow >> 4) * 2 + skc2) * 64 + squad * 16 +
              (((srow & 15) + squad + 4 * skc2) & 15);
  const float* xp = x + (size_t)(mt * 32 + srow) * Cc + scg * 8;
  int aslot[2][2];
#pragma unroll
  for (int g2 = 0; g2 < 2; ++g2)
#pragma unroll
    for (int kc2 = 0; kc2 < 2; ++kc2)
      aslot[g2][kc2] = ((g2 * 2 + kc2) * 64 + quad * 16 +
                        ((lrow + quad + 4 * kc2) & 15)) * 8;
  const unsigned short* wbase[3];
#pragma unroll
  for (int j = 0; j < 3; ++j)
    wbase[j] = WTf + (size_t)(wv * 3 + j) * 32 * 512 + lane * 8;
  {
    float4 v0 = *(const float4*)xp;
    float4 v1 = *(const float4*)(xp + 4);
    short8 a;
    a[0] = (short)f2bf(v0.x); a[1] = (short)f2bf(v0.y);
    a[2] = (short)f2bf(v0.z); a[3] = (short)f2bf(v0.w);
    a[4] = (short)f2bf(v1.x); a[5] = (short)f2bf(v1.y);
    a[6] = (short)f2bf(v1.z); a[7] = (short)f2bf(v1.w);
    *(short8*)&smem7[sslot * 8] = a;
  }
  __syncthreads();
  for (int kk = 0; kk < 16; ++kk) {
    int cur = kk & 1;
    float4 v0, v1;
    if (kk < 15) {
      v0 = *(const float4*)(xp + (kk + 1) * 64);
      v1 = *(const float4*)(xp + (kk + 1) * 64 + 4);
    }
    short8 bfr[3][2];
    int kg = kk * 2;
#pragma unroll
    for (int j = 0; j < 3; ++j)
#pragma unroll
      for (int kc2 = 0; kc2 < 2; ++kc2)
        bfr[j][kc2] = *(const short8*)(wbase[j] + (size_t)(kg + kc2) * 512);
    short8 af[2][2];
#pragma unroll
    for (int g2 = 0; g2 < 2; ++g2)
#pragma unroll
      for (int kc2 = 0; kc2 < 2; ++kc2)
        af[g2][kc2] = *(const short8*)&smem7[cur * 2048 + aslot[g2][kc2]];
#pragma unroll
    for (int g2 = 0; g2 < 2; ++g2)
#pragma unroll
      for (int j = 0; j < 3; ++j) {
        acc[g2][j] = __builtin_amdgcn_mfma_f32_16x16x32_bf16(af[g2][0], bfr[j][0], acc[g2][j], 0, 0, 0);
        acc[g2][j] = __builtin_amdgcn_mfma_f32_16x16x32_bf16(af[g2][1], bfr[j][1], acc[g2][j], 0, 0, 0);
      }
    if (kk < 15) {
      short8 a;
      a[0] = (short)f2bf(v0.x); a[1] = (short)f2bf(v0.y);
      a[2] = (short)f2bf(v0.z); a[3] = (short)f2bf(v0.w);
      a[4] = (short)f2bf(v1.x); a[5] = (short)f2bf(v1.y);
      a[6] = (short)f2bf(v1.z); a[7] = (short)f2bf(v1.w);
      *(short8*)&smem7[(1 - cur) * 2048 + sslot * 8] = a;
      __syncthreads();
    }
  }
  __syncthreads();
#pragma unroll
  for (int g2 = 0; g2 < 2; ++g2)
#pragma unroll
    for (int j = 0; j < 3; ++j) {
      int col = (wv * 3 + j) * 16 + lrow;
#pragma unroll
      for (int r = 0; r < 4; ++r)
        smem7[(g2 * 16 + quad * 4 + r) * 208 + col] = f2bf(acc[g2][j][r]);
    }
  __syncthreads();
#pragma unroll
  for (int fi = 0; fi < 3; ++fi) {
    int idx = fi * 256 + t;
    if (idx < 512) {
      int which = idx >> 8;
      int sub = idx & 255;
      int g2k = sub >> 6, lane_s = sub & 63;
      int g2_ = g2k >> 1, kc_ = g2k & 1;
      int tokrow = g2_ * 16 + (lane_s & 15);
      int hbase = which * 64 + kc_ * 32 + (lane_s >> 4) * 8;
      short8 v = *(const short8*)&smem7[tokrow * 208 + hbase];
      unsigned short* dstf = which ? Kf : Qf;
      *(short8*)&dstf[((size_t)(mt * 2 + g2_) * 2 + kc_) * 512 + lane_s * 8] = v;
    } else {
      int sub = idx - 512;
      int hs = sub >> 6, lane_s = sub & 63;
      int hcol = 128 + hs * 16 + (lane_s & 15);
      int tok0 = (lane_s >> 4) * 8;
      unsigned short tmp[8];
#pragma unroll
      for (int jj = 0; jj < 8; ++jj) tmp[jj] = smem7[(tok0 + jj) * 208 + hcol];
      unsigned short* dv = &Vf[((size_t)(mt * 4 + hs)) * 512 + lane_s * 8];
      *(ushort4*)dv = make_ushort4(tmp[0], tmp[1], tmp[2], tmp[3]);
      *(ushort4*)(dv + 4) = make_ushort4(tmp[4], tmp[5], tmp[6], tmp[7]);
    }
  }
}

__global__ __launch_bounds__(512) void attn6(
    const unsigned short* __restrict__ Qf, const unsigned short* __restrict__ Kf,
    const unsigned short* __restrict__ Vf, float* __restrict__ out) {
  __shared__ __align__(16) unsigned char smem[33 * 1024];
  unsigned short* Pall = (unsigned short*)smem;
  unsigned short* Ocomb = (unsigned short*)smem;
  float* Lcomb = (float*)(smem + 32768);
  int bid = blockIdx.x;
  int b = bid >> 5;
  int j = bid & 31;
  int t = threadIdx.x;
  int wv = t >> 6, lane = t & 63;
  int lrow = lane & 15, quad = lane >> 4;
  unsigned short* Pw = Pall + wv * 2048;
  short8 ones;
#pragma unroll
  for (int i = 0; i < 8; ++i) ones[i] = (short)0x3F80;
  for (int half = 0; half < 2; ++half) {
    int qt = half ? (63 - j) : j;
    int q0 = qt * 32;
    int nkt = (qt >> 1) + 1;
    int qtile16 = b * 128 + qt * 2;
    short8 aq[2][2];
#pragma unroll
    for (int qs = 0; qs < 2; ++qs)
#pragma unroll
      for (int kc = 0; kc < 2; ++kc)
        aq[qs][kc] = *(const short8*)
            &Qf[((size_t)(qtile16 + qs) * 2 + kc) * 512 + lane * 8];
    floatx4 acc_o[2][4];
    floatx4 acc_l[2];
#pragma unroll
    for (int qs = 0; qs < 2; ++qs) {
#pragma unroll
      for (int r = 0; r < 4; ++r) acc_l[qs][r] = 0.f;
#pragma unroll
      for (int hs = 0; hs < 4; ++hs)
#pragma unroll
        for (int r = 0; r < 4; ++r) acc_o[qs][hs][r] = 0.f;
    }
    for (int kt = wv; kt < nkt; kt += 8) {
      int ktile16 = b * 128 + kt * 4;
      int ktile32 = b * 64 + kt * 2;
      short8 kf[4][2], vf[4][2];
#pragma unroll
      for (int sn = 0; sn < 4; ++sn)
#pragma unroll
        for (int kc = 0; kc < 2; ++kc)
          kf[sn][kc] = *(const short8*)
              &Kf[((size_t)(ktile16 + sn) * 2 + kc) * 512 + lane * 8];
#pragma unroll
      for (int hs = 0; hs < 4; ++hs)
#pragma unroll
        for (int kc = 0; kc < 2; ++kc)
          vf[hs][kc] = *(const short8*)
              &Vf[((size_t)(ktile32 + kc) * 4 + hs) * 512 + lane * 8];
      floatx4 s[2][4];
#pragma unroll
      for (int qs = 0; qs < 2; ++qs)
#pragma unroll
        for (int sn = 0; sn < 4; ++sn) {
          floatx4 z;
#pragma unroll
          for (int r = 0; r < 4; ++r) z[r] = 0.f;
          z = __builtin_amdgcn_mfma_f32_16x16x32_bf16(aq[qs][0], kf[sn][0], z, 0, 0, 0);
          z = __builtin_amdgcn_mfma_f32_16x16x32_bf16(aq[qs][1], kf[sn][1], z, 0, 0, 0);
          s[qs][sn] = z;
        }
      bool diag = (kt == nkt - 1);
#pragma unroll
      for (int qs = 0; qs < 2; ++qs)
#pragma unroll
        for (int sn = 0; sn < 4; ++sn) {
          int k5 = (sn & 1) * 16 + lrow;
          int slot = qs * 2 + (sn >> 1);
          int rlbase = (k5 >> 3) * 16;
#pragma unroll
          for (int r = 0; r < 4; ++r) {
            float v = s[qs][sn][r] * SLOG2E;
            if (diag) {
              int gk = kt * 64 + sn * 16 + lrow;
              int gq = q0 + qs * 16 + quad * 4 + r;
              if (gk > gq) v = -INFINITY;
            }
            float p = exp2f(v);
            Pw[slot * 512 + (rlbase + quad * 4 + r) * 8 + (k5 & 7)] = f2bf(p);
          }
        }
      short8 ap[2][2];
#pragma unroll
      for (int qs = 0; qs < 2; ++qs)
#pragma unroll
        for (int kc = 0; kc < 2; ++kc)
          ap[qs][kc] = *(const short8*)&Pw[(qs * 2 + kc) * 512 + lane * 8];
#pragma unroll
      for (int qs = 0; qs < 2; ++qs) {
        acc_l[qs] = __builtin_amdgcn_mfma_f32_16x16x32_bf16(ap[qs][0], ones, acc_l[qs], 0, 0, 0);
        acc_l[qs] = __builtin_amdgcn_mfma_f32_16x16x32_bf16(ap[qs][1], ones, acc_l[qs], 0, 0, 0);
#pragma unroll
        for (int hs = 0; hs < 4; ++hs) {
          acc_o[qs][hs] = __builtin_amdgcn_mfma_f32_16x16x32_bf16(ap[qs][0], vf[hs][0], acc_o[qs][hs], 0, 0, 0);
          acc_o[qs][hs] = __builtin_amdgcn_mfma_f32_16x16x32_bf16(ap[qs][1], vf[hs][1], acc_o[qs][hs], 0, 0, 0);
        }
      }
    }
#pragma unroll
    for (int qs = 0; qs < 2; ++qs)
#pragma unroll
      for (int hs = 0; hs < 4; ++hs) {
        int s8 = qs * 4 + hs;
        *(ushort4*)&Ocomb[((wv * 8 + s8) * 64 + lane) * 4] =
            make_ushort4(f2bf(acc_o[qs][hs][0]), f2bf(acc_o[qs][hs][1]),
                         f2bf(acc_o[qs][hs][2]), f2bf(acc_o[qs][hs][3]));
      }
    if (lrow == 0) {
#pragma unroll
      for (int qs = 0; qs < 2; ++qs)
#pragma unroll
        for (int r = 0; r < 4; ++r)
          Lcomb[wv * 32 + qs * 16 + quad * 4 + r] = acc_l[qs][r];
    }
    __syncthreads();
    {
      int qsub = wv >> 2, hs = wv & 3;
      float o[4] = {0.f, 0.f, 0.f, 0.f};
#pragma unroll
      for (int w = 0; w < 8; ++w) {
        ushort4 pk = *(const ushort4*)&Ocomb[((w * 8 + wv) * 64 + lane) * 4];
        o[0] += bf2f(pk.x); o[1] += bf2f(pk.y);
        o[2] += bf2f(pk.z); o[3] += bf2f(pk.w);
      }
#pragma unroll
      for (int r = 0; r < 4; ++r) {
        float lv = 0.f;
#pragma unroll
        for (int w = 0; w < 8; ++w)
          lv += Lcomb[w * 32 + qsub * 16 + quad * 4 + r];
        int row = q0 + qsub * 16 + quad * 4 + r;
        out[(size_t)(b * Tt + row) * Hh + hs * 16 + lrow] = o[r] / lv;
      }
    }
    __syncthreads();
  }
}

extern "C" void kernel_launch(void* const* d_in, const int* in_sizes, int n_in,
                              void* d_out, int out_size, void* d_ws, size_t ws_size,
                              hipStream_t stream) {
  const float* x = (const float*)d_in[0];
  const float* Wq = (const float*)d_in[1];
  const float* Wk = (const float*)d_in[2];
  const float* Wv = (const float*)d_in[3];
  float* out = (float*)d_out;

  unsigned short* WTf = (unsigned short*)d_ws;            // 192*1024
  unsigned short* Qf = WTf + 192 * 1024;                  // (BT/16)*2*512
  unsigned short* Kf = Qf + (size_t)(BT / 16) * 2 * 512;
  unsigned short* Vf = Kf + (size_t)(BT / 16) * 2 * 512;  // (BT/32)*4*512

  void* kargs[] = {(void*)&x, (void*)&Wq, (void*)&Wk, (void*)&Wv,
                   (void*)&WTf, (void*)&Qf, (void*)&Kf, (void*)&Vf,
                   (void*)&out};
  hipError_t ce = hipLaunchCooperativeKernel((const void*)fused, dim3(256),
                                             dim3(512), kargs, 0, stream);
  if (ce != hipSuccess) {
    // fallback: non-cooperative 3-kernel path
    wconv2<<<dim3(96), dim3(256), 0, stream>>>(Wq, Wk, Wv, WTf);
    qkv7<<<dim3(512), dim3(256), 0, stream>>>(x, WTf, Qf, Kf, Vf);
    attn6<<<dim3(256), dim3(512), 0, stream>>>(Qf, Kf, Vf, out);
  }
}